// Round 1
// baseline (524.672 us; speedup 1.0000x reference)
//
#include <hip/hip_runtime.h>

#define EMBED 1024
#define C3    3072
#define NHEAD 16
#define HDIM  64
#define BB    4
#define TT    2048
#define MTOK  8192   // BB*TT

typedef __bf16 bf16;
typedef __bf16 bf16x4 __attribute__((ext_vector_type(4)));
typedef __bf16 bf16x8 __attribute__((ext_vector_type(8)));
typedef float  f32x4  __attribute__((ext_vector_type(4)));

__device__ __forceinline__ void gload_lds16(const bf16* g, bf16* l) {
  __builtin_amdgcn_global_load_lds((__attribute__((address_space(1))) void*)g,
                                   (__attribute__((address_space(3))) void*)l,
                                   16, 0, 0);
}

// ---------------- fp32 -> bf16 convert ----------------
__global__ __launch_bounds__(256) void cvt_kernel(const float* __restrict__ in,
                                                  bf16* __restrict__ out, int n) {
  int i = (blockIdx.x * blockDim.x + threadIdx.x) * 4;
  if (i >= n) return;
  float4 v = *reinterpret_cast<const float4*>(in + i);
  bf16x4 o;
  o[0] = (bf16)v.x; o[1] = (bf16)v.y; o[2] = (bf16)v.z; o[3] = (bf16)v.w;
  *reinterpret_cast<bf16x4*>(out + i) = o;
}

// ---------------- GEMM: C[M,N] = A[M,K] @ W[N,K]^T + bias ----------------
// m97 structure: 128x128 tile, BK=32, 4 waves each own 64x64 quadrant.
__global__ __launch_bounds__(256) void gemm_bt(const bf16* __restrict__ A,
                                               const bf16* __restrict__ W,
                                               const float* __restrict__ bias,
                                               float* __restrict__ Cf,   // fp32 out (or null)
                                               bf16* __restrict__ Cb,    // bf16 out (or null)
                                               int M, int N, int K) {
  __shared__ __align__(16) bf16 lA[128 * 32];
  __shared__ __align__(16) bf16 lB[128 * 32];
  const int tid  = threadIdx.x;
  const int lane = tid & 63;
  const int wave = tid >> 6;
  const int wm   = (wave >> 1) * 64;
  const int wn   = (wave & 1) * 64;
  const int bn0  = blockIdx.x * 128;
  const int bm0  = blockIdx.y * 128;
  const int l15  = lane & 15, lg = lane >> 4;
  const int srow = tid >> 2;      // 0..63 (64 rows per staging call)
  const int sseg = tid & 3;       // 4 x 16B segments per 64B row

  f32x4 acc[4][4] = {};

  for (int kt = 0; kt < K; kt += 32) {
#pragma unroll
    for (int c = 0; c < 2; ++c) {
      int row = c * 64 + srow;
      gload_lds16(A + (size_t)(bm0 + row) * K + kt + sseg * 8, &lA[(c * 256 + tid) * 8]);
      gload_lds16(W + (size_t)(bn0 + row) * K + kt + sseg * 8, &lB[(c * 256 + tid) * 8]);
    }
    __syncthreads();
    bf16x8 af[4], bf_[4];
#pragma unroll
    for (int i = 0; i < 4; ++i)
      af[i] = *reinterpret_cast<const bf16x8*>(&lA[(wm + i * 16 + l15) * 32 + lg * 8]);
#pragma unroll
    for (int j = 0; j < 4; ++j)
      bf_[j] = *reinterpret_cast<const bf16x8*>(&lB[(wn + j * 16 + l15) * 32 + lg * 8]);
#pragma unroll
    for (int i = 0; i < 4; ++i)
#pragma unroll
      for (int j = 0; j < 4; ++j)
        acc[i][j] = __builtin_amdgcn_mfma_f32_16x16x32_bf16(af[i], bf_[j], acc[i][j], 0, 0, 0);
    __syncthreads();
  }

#pragma unroll
  for (int i = 0; i < 4; ++i)
#pragma unroll
    for (int j = 0; j < 4; ++j) {
      int col = bn0 + wn + j * 16 + l15;
      float bs = bias ? bias[col] : 0.0f;
#pragma unroll
      for (int r = 0; r < 4; ++r) {
        int row = bm0 + wm + i * 16 + lg * 4 + r;
        float v = acc[i][j][r] + bs;
        if (Cf) Cf[(size_t)row * N + col] = v;
        else    Cb[(size_t)row * N + col] = (bf16)v;
      }
    }
}

// ---------------- causal flash attention ----------------
// block = (qtile of 64 rows, b*H+h); 4 waves x 16 q-rows; KV tiles of 32.
__global__ __launch_bounds__(256) void attn_kernel(const bf16* __restrict__ qkv, // [MTOK][3072]
                                                   bf16* __restrict__ aout) {     // [MTOK][1024]
  __shared__ __align__(16) bf16 lK[32 * 64];      // K tile, seg-XOR swizzled
  __shared__ __align__(16) bf16 lV[64 * 40];      // V^T, padded stride 40
  __shared__ __align__(16) bf16 lP[4][16 * 40];   // per-wave P, padded stride 40
  const int tid  = threadIdx.x;
  const int lane = tid & 63, wave = tid >> 6;
  const int l15  = lane & 15, lg = lane >> 4;
  const int qtile = blockIdx.x;          // 0..31
  const int bh    = blockIdx.y;          // 0..63
  const int b     = bh >> 4, h = bh & 15;
  const int q0    = qtile * 64 + wave * 16;
  const size_t tbase = (size_t)b * TT;

  // Q fragments (reused for the whole KV loop)
  bf16x8 qf[2];
  {
    const bf16* qrow = qkv + (tbase + q0 + l15) * (size_t)C3 + h * HDIM;
    qf[0] = *reinterpret_cast<const bf16x8*>(qrow + lg * 8);
    qf[1] = *reinterpret_cast<const bf16x8*>(qrow + 32 + lg * 8);
  }

  f32x4 oacc[4] = {};
  float mrun[4], srun[4];
#pragma unroll
  for (int r = 0; r < 4; ++r) { mrun[r] = -1e30f; srun[r] = 0.0f; }

  const int nkv  = (qtile + 1) * 2;
  const int krow = tid >> 3;   // 0..31
  const int kseg = tid & 7;    // 8 x 16B segments per 128B row

  for (int t = 0; t < nkv; ++t) {
    const int kv0 = t * 32;
    // stage K with pre-swizzled global source (seg ^= row&7) -> linear LDS dest
    gload_lds16(qkv + (tbase + kv0 + krow) * (size_t)C3 + EMBED + h * HDIM + (kseg ^ (krow & 7)) * 8,
                &lK[tid * 8]);
    // stage V transposed (reg -> LDS, padded rows)
    {
      bf16x8 vv = *reinterpret_cast<const bf16x8*>(
          qkv + (tbase + kv0 + krow) * (size_t)C3 + 2 * EMBED + h * HDIM + kseg * 8);
#pragma unroll
      for (int j = 0; j < 8; ++j) lV[(kseg * 8 + j) * 40 + krow] = vv[j];
    }
    __syncthreads();

    // S = (Q K^T) * scale, with causal mask
    f32x4 s[2];
#pragma unroll
    for (int nf = 0; nf < 2; ++nf) {
      int row = nf * 16 + l15;
      int sw  = (row & 7) << 4;
      const char* kbase = (const char*)lK + row * 128;
      bf16x8 k0 = *reinterpret_cast<const bf16x8*>(kbase + ((lg * 16) ^ sw));
      bf16x8 k1 = *reinterpret_cast<const bf16x8*>(kbase + ((lg * 16 + 64) ^ sw));
      f32x4 z = {};
      z = __builtin_amdgcn_mfma_f32_16x16x32_bf16(qf[0], k0, z, 0, 0, 0);
      z = __builtin_amdgcn_mfma_f32_16x16x32_bf16(qf[1], k1, z, 0, 0, 0);
      s[nf] = z;
    }
#pragma unroll
    for (int nf = 0; nf < 2; ++nf)
#pragma unroll
      for (int r = 0; r < 4; ++r) {
        int qg = q0 + lg * 4 + r;
        int kv = kv0 + nf * 16 + l15;
        float v = s[nf][r] * 0.125f;
        s[nf][r] = (kv <= qg) ? v : -1e30f;
      }

    // online softmax (per q-row r; cols live across the 16-lane group)
    float pr0[4], pr1[4];
#pragma unroll
    for (int r = 0; r < 4; ++r) {
      float mx = fmaxf(s[0][r], s[1][r]);
#pragma unroll
      for (int off = 1; off < 16; off <<= 1) mx = fmaxf(mx, __shfl_xor(mx, off));
      float mnew = fmaxf(mrun[r], mx);
      float corr = __expf(mrun[r] - mnew);
      float p0 = __expf(s[0][r] - mnew);
      float p1 = __expf(s[1][r] - mnew);
      float rs = p0 + p1;
#pragma unroll
      for (int off = 1; off < 16; off <<= 1) rs += __shfl_xor(rs, off);
      srun[r] = srun[r] * corr + rs;
      mrun[r] = mnew;
#pragma unroll
      for (int nf = 0; nf < 4; ++nf) oacc[nf][r] *= corr;
      pr0[r] = p0; pr1[r] = p1;
    }

    // P (D-layout) -> LDS -> A-frag layout
    bf16* pw = &lP[wave][0];
#pragma unroll
    for (int r = 0; r < 4; ++r) {
      pw[(lg * 4 + r) * 40 + l15]      = (bf16)pr0[r];
      pw[(lg * 4 + r) * 40 + 16 + l15] = (bf16)pr1[r];
    }
    bf16x8 pa = *reinterpret_cast<const bf16x8*>(&pw[l15 * 40 + lg * 8]);
#pragma unroll
    for (int nf = 0; nf < 4; ++nf) {
      bf16x8 vb = *reinterpret_cast<const bf16x8*>(&lV[(nf * 16 + l15) * 40 + lg * 8]);
      oacc[nf] = __builtin_amdgcn_mfma_f32_16x16x32_bf16(pa, vb, oacc[nf], 0, 0, 0);
    }
    __syncthreads();
  }

  // epilogue: O /= rowsum, store bf16 [token][h*64+d]
#pragma unroll
  for (int nf = 0; nf < 4; ++nf)
#pragma unroll
    for (int r = 0; r < 4; ++r) {
      int qg = q0 + lg * 4 + r;
      float v = oacc[nf][r] / srun[r];
      aout[(tbase + qg) * (size_t)EMBED + h * HDIM + nf * 16 + l15] = (bf16)v;
    }
}

extern "C" void kernel_launch(void* const* d_in, const int* in_sizes, int n_in,
                              void* d_out, int out_size, void* d_ws, size_t ws_size,
                              hipStream_t stream) {
  const float* x      = (const float*)d_in[0];
  const float* qkv_w  = (const float*)d_in[1];
  const float* qkv_b  = (const float*)d_in[2];
  const float* proj_w = (const float*)d_in[3];
  const float* proj_b = (const float*)d_in[4];
  float* out = (float*)d_out;

  char* ws = (char*)d_ws;
  bf16* xb    = (bf16*)ws;                                   // 8192*1024  (16.8 MB)
  bf16* wqkv  = xb + (size_t)MTOK * EMBED;                   // 3072*1024  ( 6.3 MB)
  bf16* wproj = wqkv + (size_t)C3 * EMBED;                   // 1024*1024  ( 2.1 MB)
  bf16* qkvb  = wproj + (size_t)EMBED * EMBED;               // 8192*3072  (50.3 MB)
  bf16* aob   = xb;  // alias: xb dead after GEMM1

  cvt_kernel<<<dim3((MTOK * EMBED / 4 + 255) / 256), dim3(256), 0, stream>>>(x, xb, MTOK * EMBED);
  cvt_kernel<<<dim3((C3 * EMBED / 4 + 255) / 256), dim3(256), 0, stream>>>(qkv_w, wqkv, C3 * EMBED);
  cvt_kernel<<<dim3((EMBED * EMBED / 4 + 255) / 256), dim3(256), 0, stream>>>(proj_w, wproj, EMBED * EMBED);

  gemm_bt<<<dim3(C3 / 128, MTOK / 128), dim3(256), 0, stream>>>(
      xb, wqkv, qkv_b, nullptr, qkvb, MTOK, C3, EMBED);

  attn_kernel<<<dim3(TT / 64, BB * NHEAD), dim3(256), 0, stream>>>(qkvb, aob);

  gemm_bt<<<dim3(EMBED / 128, MTOK / 128), dim3(256), 0, stream>>>(
      aob, wproj, proj_b, out, nullptr, MTOK, EMBED, EMBED);
}

// Round 2
// 205.994 us; speedup vs baseline: 2.5470x; 2.5470x over previous
//
#include <hip/hip_runtime.h>

#define EMBED 1024
#define C3    3072
#define NHEAD 16
#define HDIM  64
#define BB    4
#define TT    2048
#define MTOK  8192   // BB*TT

typedef __bf16 bf16;
typedef __bf16 bf16x4 __attribute__((ext_vector_type(4)));
typedef __bf16 bf16x8 __attribute__((ext_vector_type(8)));
typedef float  f32x4  __attribute__((ext_vector_type(4)));
typedef unsigned int u32;

__device__ __forceinline__ void gload_lds16(const bf16* g, bf16* l) {
  __builtin_amdgcn_global_load_lds((__attribute__((address_space(1))) void*)g,
                                   (__attribute__((address_space(3))) void*)l,
                                   16, 0, 0);
}

// ---------------- fp32 -> bf16 convert ----------------
__global__ __launch_bounds__(256) void cvt_kernel(const float* __restrict__ in,
                                                  bf16* __restrict__ out, int n) {
  int i = (blockIdx.x * blockDim.x + threadIdx.x) * 4;
  if (i >= n) return;
  float4 v = *reinterpret_cast<const float4*>(in + i);
  bf16x4 o;
  o[0] = (bf16)v.x; o[1] = (bf16)v.y; o[2] = (bf16)v.z; o[3] = (bf16)v.w;
  *reinterpret_cast<bf16x4*>(out + i) = o;
}

// ---------------- GEMM1: qkv = x @ qkv_w^T + b, split into per-head layouts --------
// Qh/Kh: [bh][t][64] row-major ; VhT: [bh][64][t] (transposed)
__global__ __launch_bounds__(256) void gemm_qkv(const bf16* __restrict__ A,   // [8192][1024]
                                                const bf16* __restrict__ W,   // [3072][1024]
                                                const float* __restrict__ bias,
                                                bf16* __restrict__ Qh,
                                                bf16* __restrict__ Kh,
                                                bf16* __restrict__ VhT) {
  const int K = EMBED, N = C3;
  __shared__ __align__(16) bf16 lA[128 * 32];
  __shared__ __align__(16) bf16 lB[128 * 32];
  const int tid  = threadIdx.x;
  const int lane = tid & 63;
  const int wave = tid >> 6;
  const int wm   = (wave >> 1) * 64;
  const int wn   = (wave & 1) * 64;
  const int bn0  = blockIdx.x * 128;
  const int bm0  = blockIdx.y * 128;
  const int l15  = lane & 15, lg = lane >> 4;
  const int srow = tid >> 2;
  const int sseg = tid & 3;

  f32x4 acc[4][4] = {};

  for (int kt = 0; kt < K; kt += 32) {
#pragma unroll
    for (int c = 0; c < 2; ++c) {
      int row = c * 64 + srow;
      gload_lds16(A + (size_t)(bm0 + row) * K + kt + sseg * 8, &lA[(c * 256 + tid) * 8]);
      gload_lds16(W + (size_t)(bn0 + row) * K + kt + sseg * 8, &lB[(c * 256 + tid) * 8]);
    }
    __syncthreads();
    bf16x8 af[4], bf_[4];
#pragma unroll
    for (int i = 0; i < 4; ++i)
      af[i] = *reinterpret_cast<const bf16x8*>(&lA[(wm + i * 16 + l15) * 32 + lg * 8]);
#pragma unroll
    for (int j = 0; j < 4; ++j)
      bf_[j] = *reinterpret_cast<const bf16x8*>(&lB[(wn + j * 16 + l15) * 32 + lg * 8]);
#pragma unroll
    for (int i = 0; i < 4; ++i)
#pragma unroll
      for (int j = 0; j < 4; ++j)
        acc[i][j] = __builtin_amdgcn_mfma_f32_16x16x32_bf16(af[i], bf_[j], acc[i][j], 0, 0, 0);
    __syncthreads();
  }

  const int sec = bn0 >> 10;   // 0=Q 1=K 2=V, uniform per block
#pragma unroll
  for (int i = 0; i < 4; ++i)
#pragma unroll
    for (int j = 0; j < 4; ++j) {
      const int col = bn0 + wn + j * 16 + l15;
      const float bs = bias[col];
      const int c2 = col & 1023, hh = c2 >> 6, dd = c2 & 63;
      const int rowb = bm0 + wm + i * 16 + lg * 4;
      const int bb = rowb >> 11, t0 = rowb & 2047;
      const int bh = bb * 16 + hh;
      if (sec < 2) {
        bf16* dst = (sec ? Kh : Qh) + ((size_t)bh * TT + t0) * HDIM + dd;
#pragma unroll
        for (int r = 0; r < 4; ++r) dst[(size_t)r * HDIM] = (bf16)(acc[i][j][r] + bs);
      } else {
        bf16x4 o4;
#pragma unroll
        for (int r = 0; r < 4; ++r) o4[r] = (bf16)(acc[i][j][r] + bs);
        *reinterpret_cast<bf16x4*>(VhT + ((size_t)bh * HDIM + dd) * TT + t0) = o4;
      }
    }
}

// ---------------- GEMM2: out = A @ W^T + b (fp32 out) ----------------
__global__ __launch_bounds__(256) void gemm_bt(const bf16* __restrict__ A,
                                               const bf16* __restrict__ W,
                                               const float* __restrict__ bias,
                                               float* __restrict__ Cf,
                                               int M, int N, int K) {
  __shared__ __align__(16) bf16 lA[128 * 32];
  __shared__ __align__(16) bf16 lB[128 * 32];
  const int tid  = threadIdx.x;
  const int lane = tid & 63;
  const int wave = tid >> 6;
  const int wm   = (wave >> 1) * 64;
  const int wn   = (wave & 1) * 64;
  const int bn0  = blockIdx.x * 128;
  const int bm0  = blockIdx.y * 128;
  const int l15  = lane & 15, lg = lane >> 4;
  const int srow = tid >> 2;
  const int sseg = tid & 3;

  f32x4 acc[4][4] = {};

  for (int kt = 0; kt < K; kt += 32) {
#pragma unroll
    for (int c = 0; c < 2; ++c) {
      int row = c * 64 + srow;
      gload_lds16(A + (size_t)(bm0 + row) * K + kt + sseg * 8, &lA[(c * 256 + tid) * 8]);
      gload_lds16(W + (size_t)(bn0 + row) * K + kt + sseg * 8, &lB[(c * 256 + tid) * 8]);
    }
    __syncthreads();
    bf16x8 af[4], bf_[4];
#pragma unroll
    for (int i = 0; i < 4; ++i)
      af[i] = *reinterpret_cast<const bf16x8*>(&lA[(wm + i * 16 + l15) * 32 + lg * 8]);
#pragma unroll
    for (int j = 0; j < 4; ++j)
      bf_[j] = *reinterpret_cast<const bf16x8*>(&lB[(wn + j * 16 + l15) * 32 + lg * 8]);
#pragma unroll
    for (int i = 0; i < 4; ++i)
#pragma unroll
      for (int j = 0; j < 4; ++j)
        acc[i][j] = __builtin_amdgcn_mfma_f32_16x16x32_bf16(af[i], bf_[j], acc[i][j], 0, 0, 0);
    __syncthreads();
  }

#pragma unroll
  for (int i = 0; i < 4; ++i)
#pragma unroll
    for (int j = 0; j < 4; ++j) {
      int col = bn0 + wn + j * 16 + l15;
      float bs = bias[col];
#pragma unroll
      for (int r = 0; r < 4; ++r) {
        int row = bm0 + wm + i * 16 + lg * 4 + r;
        Cf[(size_t)row * N + col] = acc[i][j][r] + bs;
      }
    }
}

// ---------------- causal flash attention (swapped-operand layout) ----------------
// block: 256 thr = 4 waves; QBLK=128 (32 q/wave, 2 frags), KVBLK=64, dbuf LDS.
__global__ __launch_bounds__(256) void attn_kernel(const bf16* __restrict__ Qh,
                                                   const bf16* __restrict__ Kh,
                                                   const bf16* __restrict__ VhT,
                                                   bf16* __restrict__ aout) {
  __shared__ __align__(16) bf16 lK[2][64 * 64];
  __shared__ __align__(16) bf16 lVT[2][64 * 64];
  const int tid  = threadIdx.x;
  const int lane = tid & 63, wave = tid >> 6;
  const int l15  = lane & 15, lg = lane >> 4;
  const int bh   = blockIdx.x;              // 0..63
  const int qt   = 15 - blockIdx.y;         // heavy bands dispatched first
  const int b    = bh >> 4, h = bh & 15;
  const int q0w  = qt * 128 + wave * 32;
  const size_t tb = (size_t)b * TT;

  // Q fragments, pre-scaled by 0.125*log2(e) so softmax runs in exp2 domain
  const float QSCALE = 0.18033688011112042f;
  bf16x8 qfr[2][2];
#pragma unroll
  for (int qf = 0; qf < 2; ++qf) {
    const bf16* qrow = Qh + ((size_t)bh * TT + q0w + qf * 16 + l15) * HDIM;
#pragma unroll
    for (int dc = 0; dc < 2; ++dc) {
      bf16x8 v = *reinterpret_cast<const bf16x8*>(qrow + dc * 32 + lg * 8);
      bf16x8 o;
#pragma unroll
      for (int j = 0; j < 8; ++j) o[j] = (bf16)((float)v[j] * QSCALE);
      qfr[qf][dc] = o;
    }
  }

  f32x4 oacc[2][4] = {};        // [qf][nf] : O[q=l15][d=16nf+4lg+r]
  float mrun[2] = {-3e38f, -3e38f};
  float srun[2] = {0.0f, 0.0f};

  // staging constants (thread handles chunks c=tid and c=tid+256)
  const int r0 = tid >> 3, sg = tid & 7;
  const bf16* kS0 = Kh + ((size_t)bh * TT + r0) * HDIM + (size_t)(sg ^ (r0 & 7)) * 8;
  const bf16* kS1 = Kh + ((size_t)bh * TT + 32 + r0) * HDIM + (size_t)(sg ^ ((32 + r0) & 7)) * 8;
  const bf16* vS0 = VhT + ((size_t)bh * HDIM + r0) * TT + (size_t)(sg ^ (r0 & 7)) * 8;
  const bf16* vS1 = VhT + ((size_t)bh * HDIM + 32 + r0) * TT + (size_t)(sg ^ ((32 + r0) & 7)) * 8;

  const int nkv = 2 * qt + 2;
  const int s0l = (lane & 15) | ((lane & 16) << 1);   // src lane base for P redistribution
  const bool hi = (lane & 32) != 0;

  // prologue: stage tile 0 into buf 0
  {
    gload_lds16(kS0, &lK[0][tid * 8]);
    gload_lds16(kS1, &lK[0][(tid + 256) * 8]);
    gload_lds16(vS0, &lVT[0][tid * 8]);
    gload_lds16(vS1, &lVT[0][(tid + 256) * 8]);
  }
  __syncthreads();

  int cur = 0;
  for (int t = 0; t < nkv; ++t) {
    const int kv0 = t * 64;
    // prefetch next tile into the other buffer (overlaps with compute below)
    if (t + 1 < nkv) {
      const int kvn = kv0 + 64;
      gload_lds16(kS0 + (size_t)kvn * HDIM, &lK[cur ^ 1][tid * 8]);
      gload_lds16(kS1 + (size_t)kvn * HDIM, &lK[cur ^ 1][(tid + 256) * 8]);
      gload_lds16(vS0 + kvn, &lVT[cur ^ 1][tid * 8]);
      gload_lds16(vS1 + kvn, &lVT[cur ^ 1][(tid + 256) * 8]);
    }

    if (kv0 <= q0w + 31) {
      const char* kbase = (const char*)&lK[cur][0];
      const char* vbase = (const char*)&lVT[cur][0];
      // K fragments: lane holds K[kv=16nf+l15][dc*32 + lg*8 ..+8]
      bf16x8 kf[4][2];
#pragma unroll
      for (int nf = 0; nf < 4; ++nf) {
        int row = nf * 16 + l15;
#pragma unroll
        for (int dc = 0; dc < 2; ++dc)
          kf[nf][dc] = *reinterpret_cast<const bf16x8*>(
              kbase + row * 128 + (((dc * 4 + lg) * 16) ^ ((row & 7) << 4)));
      }

      u32 pk01[2][4], pk23[2][4];
      bool act[2];
#pragma unroll
      for (int qf = 0; qf < 2; ++qf) {
        const int qfq0 = q0w + qf * 16;
        act[qf] = (kv0 <= qfq0 + 15);
        if (!act[qf]) continue;
        // S^T: lane holds S[q=qfq0+l15][kv=kv0+16nf+4lg+r]  (log2 domain)
        f32x4 s[4];
#pragma unroll
        for (int nf = 0; nf < 4; ++nf) {
          f32x4 z = {};
          z = __builtin_amdgcn_mfma_f32_16x16x32_bf16(kf[nf][0], qfr[qf][0], z, 0, 0, 0);
          z = __builtin_amdgcn_mfma_f32_16x16x32_bf16(kf[nf][1], qfr[qf][1], z, 0, 0, 0);
          s[nf] = z;
        }
        const int qg = qfq0 + l15;
        if (kv0 + 63 > qfq0) {   // diagonal-crossing: apply causal mask
#pragma unroll
          for (int nf = 0; nf < 4; ++nf)
#pragma unroll
            for (int r = 0; r < 4; ++r) {
              int kv = kv0 + nf * 16 + 4 * lg + r;
              if (kv > qg) s[nf][r] = -3e38f;
            }
        }
        // row max (q = l15): in-lane 16, then across lg lanes
        float mx = s[0][0];
#pragma unroll
        for (int nf = 0; nf < 4; ++nf)
#pragma unroll
          for (int r = 0; r < 4; ++r) mx = fmaxf(mx, s[nf][r]);
        mx = fmaxf(mx, __shfl_xor(mx, 16));
        mx = fmaxf(mx, __shfl_xor(mx, 32));
        const float mnew = fmaxf(mrun[qf], mx);
        const float corr = __builtin_amdgcn_exp2f(mrun[qf] - mnew);
        mrun[qf] = mnew;
        float psum = 0.0f;
#pragma unroll
        for (int nf = 0; nf < 4; ++nf) {
          float p0 = __builtin_amdgcn_exp2f(s[nf][0] - mnew);
          float p1 = __builtin_amdgcn_exp2f(s[nf][1] - mnew);
          float p2 = __builtin_amdgcn_exp2f(s[nf][2] - mnew);
          float p3 = __builtin_amdgcn_exp2f(s[nf][3] - mnew);
          psum += (p0 + p1) + (p2 + p3);
          union { bf16 hh[2]; u32 w; } u01, u23;
          u01.hh[0] = (bf16)p0; u01.hh[1] = (bf16)p1;
          u23.hh[0] = (bf16)p2; u23.hh[1] = (bf16)p3;
          pk01[qf][nf] = u01.w; pk23[qf][nf] = u23.w;
        }
        srun[qf] = srun[qf] * corr + psum;
#pragma unroll
        for (int nf = 0; nf < 4; ++nf) {
          oacc[qf][nf][0] *= corr; oacc[qf][nf][1] *= corr;
          oacc[qf][nf][2] *= corr; oacc[qf][nf][3] *= corr;
        }
      }

      // PV: O[q][d] += P[q][kv] V[kv][d], via mfma(A=V^T-frag, B=P-frag)
#pragma unroll
      for (int w = 0; w < 2; ++w) {
        bf16x8 vf[4];
#pragma unroll
        for (int nf = 0; nf < 4; ++nf) {
          int row = nf * 16 + l15;
          vf[nf] = *reinterpret_cast<const bf16x8*>(
              vbase + row * 128 + (((w * 4 + lg) * 16) ^ ((row & 7) << 4)));
        }
#pragma unroll
        for (int qf = 0; qf < 2; ++qf) {
          if (!act[qf]) continue;
          // redistribute P: lane needs P[q=l15][kv=32w+8lg+j], j=0..7
          u32 a0 = __shfl((int)pk01[qf][2 * w],     s0l);
          u32 b0 = __shfl((int)pk01[qf][2 * w + 1], s0l);
          u32 a1 = __shfl((int)pk23[qf][2 * w],     s0l);
          u32 b1 = __shfl((int)pk23[qf][2 * w + 1], s0l);
          u32 a2 = __shfl((int)pk01[qf][2 * w],     s0l + 16);
          u32 b2 = __shfl((int)pk01[qf][2 * w + 1], s0l + 16);
          u32 a3 = __shfl((int)pk23[qf][2 * w],     s0l + 16);
          u32 b3 = __shfl((int)pk23[qf][2 * w + 1], s0l + 16);
          union { u32 w4[4]; bf16x8 v; } pa;
          pa.w4[0] = hi ? b0 : a0;
          pa.w4[1] = hi ? b1 : a1;
          pa.w4[2] = hi ? b2 : a2;
          pa.w4[3] = hi ? b3 : a3;
#pragma unroll
          for (int nf = 0; nf < 4; ++nf)
            oacc[qf][nf] = __builtin_amdgcn_mfma_f32_16x16x32_bf16(vf[nf], pa.v, oacc[qf][nf], 0, 0, 0);
        }
      }
    }
    __syncthreads();   // drains prefetch vmcnt + protects dbuf swap
    cur ^= 1;
  }

  // epilogue: rowsum reduce + divide + store (q = l15 layout, pack 4 d's)
#pragma unroll
  for (int qf = 0; qf < 2; ++qf) {
    float sr = srun[qf];
    sr += __shfl_xor(sr, 16);
    sr += __shfl_xor(sr, 32);
    const float inv = 1.0f / sr;
    const int qrow = q0w + qf * 16 + l15;
    bf16* orow = aout + (tb + qrow) * (size_t)EMBED + h * HDIM;
#pragma unroll
    for (int nf = 0; nf < 4; ++nf) {
      bf16x4 o4;
#pragma unroll
      for (int r = 0; r < 4; ++r) o4[r] = (bf16)(oacc[qf][nf][r] * inv);
      *reinterpret_cast<bf16x4*>(orow + nf * 16 + lg * 4) = o4;
    }
  }
}

extern "C" void kernel_launch(void* const* d_in, const int* in_sizes, int n_in,
                              void* d_out, int out_size, void* d_ws, size_t ws_size,
                              hipStream_t stream) {
  const float* x      = (const float*)d_in[0];
  const float* qkv_w  = (const float*)d_in[1];
  const float* qkv_b  = (const float*)d_in[2];
  const float* proj_w = (const float*)d_in[3];
  const float* proj_b = (const float*)d_in[4];
  float* out = (float*)d_out;

  char* ws = (char*)d_ws;
  bf16* xb    = (bf16*)ws;                                   // 8,388,608 elems
  bf16* wqkv  = xb + (size_t)MTOK * EMBED;                   // 3,145,728
  bf16* wproj = wqkv + (size_t)C3 * EMBED;                   // 1,048,576
  bf16* Qh    = wproj + (size_t)EMBED * EMBED;               // 8,388,608
  bf16* Kh    = Qh + (size_t)MTOK * HDIM * NHEAD / NHEAD * NHEAD; // = +8,388,608
  bf16* VhT   = Kh + (size_t)BB * NHEAD * TT * HDIM;         // 8,388,608
  bf16* aob   = xb;   // alias: xb dead after gemm_qkv

  cvt_kernel<<<dim3((MTOK * EMBED / 4 + 255) / 256), dim3(256), 0, stream>>>(x, xb, MTOK * EMBED);
  cvt_kernel<<<dim3((C3 * EMBED / 4 + 255) / 256), dim3(256), 0, stream>>>(qkv_w, wqkv, C3 * EMBED);
  cvt_kernel<<<dim3((EMBED * EMBED / 4 + 255) / 256), dim3(256), 0, stream>>>(proj_w, wproj, EMBED * EMBED);

  gemm_qkv<<<dim3(C3 / 128, MTOK / 128), dim3(256), 0, stream>>>(xb, wqkv, qkv_b, Qh, Kh, VhT);

  attn_kernel<<<dim3(BB * NHEAD, TT / 128), dim3(256), 0, stream>>>(Qh, Kh, VhT, aob);

  gemm_bt<<<dim3(EMBED / 128, MTOK / 128), dim3(256), 0, stream>>>(
      aob, wproj, proj_b, out, MTOK, EMBED, EMBED);
}

// Round 4
// 190.376 us; speedup vs baseline: 2.7560x; 1.0820x over previous
//
#include <hip/hip_runtime.h>

#define EMBED 1024
#define C3    3072
#define NHEAD 16
#define HDIM  64
#define BB    4
#define TT    2048
#define MTOK  8192   // BB*TT

typedef __bf16 bf16;
typedef __bf16 bf16x4 __attribute__((ext_vector_type(4)));
typedef __bf16 bf16x8 __attribute__((ext_vector_type(8)));
typedef float  f32x4  __attribute__((ext_vector_type(4)));
typedef float  f32x16 __attribute__((ext_vector_type(16)));
typedef unsigned int u32;

__device__ __forceinline__ void gload_lds16(const bf16* g, bf16* l) {
  __builtin_amdgcn_global_load_lds((__attribute__((address_space(1))) void*)g,
                                   (__attribute__((address_space(3))) void*)l,
                                   16, 0, 0);
}

__device__ __forceinline__ u32 pkbf(float lo, float hi_) {
  union { bf16 h[2]; u32 w; } u;
  u.h[0] = (bf16)lo; u.h[1] = (bf16)hi_;
  return u.w;
}

// ---------------- fp32 -> bf16 convert ----------------
__global__ __launch_bounds__(256) void cvt_kernel(const float* __restrict__ in,
                                                  bf16* __restrict__ out, int n) {
  int i = (blockIdx.x * blockDim.x + threadIdx.x) * 4;
  if (i >= n) return;
  float4 v = *reinterpret_cast<const float4*>(in + i);
  bf16x4 o;
  o[0] = (bf16)v.x; o[1] = (bf16)v.y; o[2] = (bf16)v.z; o[3] = (bf16)v.w;
  *reinterpret_cast<bf16x4*>(out + i) = o;
}

// ---------------- GEMM1: qkv = x @ qkv_w^T + b, split into per-head layouts --------
__global__ __launch_bounds__(256) void gemm_qkv(const bf16* __restrict__ A,   // [8192][1024]
                                                const bf16* __restrict__ W,   // [3072][1024]
                                                const float* __restrict__ bias,
                                                bf16* __restrict__ Qh,
                                                bf16* __restrict__ Kh,
                                                bf16* __restrict__ VhT) {
  const int K = EMBED;
  __shared__ __align__(16) bf16 lA[128 * 32];
  __shared__ __align__(16) bf16 lB[128 * 32];
  const int tid  = threadIdx.x;
  const int lane = tid & 63;
  const int wave = tid >> 6;
  const int wm   = (wave >> 1) * 64;
  const int wn   = (wave & 1) * 64;
  const int bn0  = blockIdx.x * 128;
  const int bm0  = blockIdx.y * 128;
  const int l15  = lane & 15, lg = lane >> 4;
  const int srow = tid >> 2;
  const int sseg = tid & 3;

  f32x4 acc[4][4] = {};

  for (int kt = 0; kt < K; kt += 32) {
#pragma unroll
    for (int c = 0; c < 2; ++c) {
      int row = c * 64 + srow;
      gload_lds16(A + (size_t)(bm0 + row) * K + kt + sseg * 8, &lA[(c * 256 + tid) * 8]);
      gload_lds16(W + (size_t)(bn0 + row) * K + kt + sseg * 8, &lB[(c * 256 + tid) * 8]);
    }
    __syncthreads();
    bf16x8 af[4], bf_[4];
#pragma unroll
    for (int i = 0; i < 4; ++i)
      af[i] = *reinterpret_cast<const bf16x8*>(&lA[(wm + i * 16 + l15) * 32 + lg * 8]);
#pragma unroll
    for (int j = 0; j < 4; ++j)
      bf_[j] = *reinterpret_cast<const bf16x8*>(&lB[(wn + j * 16 + l15) * 32 + lg * 8]);
#pragma unroll
    for (int i = 0; i < 4; ++i)
#pragma unroll
      for (int j = 0; j < 4; ++j)
        acc[i][j] = __builtin_amdgcn_mfma_f32_16x16x32_bf16(af[i], bf_[j], acc[i][j], 0, 0, 0);
    __syncthreads();
  }

  const int sec = bn0 >> 10;   // 0=Q 1=K 2=V, uniform per block
#pragma unroll
  for (int i = 0; i < 4; ++i)
#pragma unroll
    for (int j = 0; j < 4; ++j) {
      const int col = bn0 + wn + j * 16 + l15;
      const float bs = bias[col];
      const int c2 = col & 1023, hh = c2 >> 6, dd = c2 & 63;
      const int rowb = bm0 + wm + i * 16 + lg * 4;
      const int bb = rowb >> 11, t0 = rowb & 2047;
      const int bh = bb * 16 + hh;
      if (sec < 2) {
        bf16* dst = (sec ? Kh : Qh) + ((size_t)bh * TT + t0) * HDIM + dd;
#pragma unroll
        for (int r = 0; r < 4; ++r) dst[(size_t)r * HDIM] = (bf16)(acc[i][j][r] + bs);
      } else {
        bf16x4 o4;
#pragma unroll
        for (int r = 0; r < 4; ++r) o4[r] = (bf16)(acc[i][j][r] + bs);
        *reinterpret_cast<bf16x4*>(VhT + ((size_t)bh * HDIM + dd) * TT + t0) = o4;
      }
    }
}

// ---------------- GEMM2: out = A @ W^T + b (fp32 out) ----------------
__global__ __launch_bounds__(256) void gemm_bt(const bf16* __restrict__ A,
                                               const bf16* __restrict__ W,
                                               const float* __restrict__ bias,
                                               float* __restrict__ Cf,
                                               int M, int N, int K) {
  __shared__ __align__(16) bf16 lA[128 * 32];
  __shared__ __align__(16) bf16 lB[128 * 32];
  const int tid  = threadIdx.x;
  const int lane = tid & 63;
  const int wave = tid >> 6;
  const int wm   = (wave >> 1) * 64;
  const int wn   = (wave & 1) * 64;
  const int bn0  = blockIdx.x * 128;
  const int bm0  = blockIdx.y * 128;
  const int l15  = lane & 15, lg = lane >> 4;
  const int srow = tid >> 2;
  const int sseg = tid & 3;

  f32x4 acc[4][4] = {};

  for (int kt = 0; kt < K; kt += 32) {
#pragma unroll
    for (int c = 0; c < 2; ++c) {
      int row = c * 64 + srow;
      gload_lds16(A + (size_t)(bm0 + row) * K + kt + sseg * 8, &lA[(c * 256 + tid) * 8]);
      gload_lds16(W + (size_t)(bn0 + row) * K + kt + sseg * 8, &lB[(c * 256 + tid) * 8]);
    }
    __syncthreads();
    bf16x8 af[4], bf_[4];
#pragma unroll
    for (int i = 0; i < 4; ++i)
      af[i] = *reinterpret_cast<const bf16x8*>(&lA[(wm + i * 16 + l15) * 32 + lg * 8]);
#pragma unroll
    for (int j = 0; j < 4; ++j)
      bf_[j] = *reinterpret_cast<const bf16x8*>(&lB[(wn + j * 16 + l15) * 32 + lg * 8]);
#pragma unroll
    for (int i = 0; i < 4; ++i)
#pragma unroll
      for (int j = 0; j < 4; ++j)
        acc[i][j] = __builtin_amdgcn_mfma_f32_16x16x32_bf16(af[i], bf_[j], acc[i][j], 0, 0, 0);
    __syncthreads();
  }

#pragma unroll
  for (int i = 0; i < 4; ++i)
#pragma unroll
    for (int j = 0; j < 4; ++j) {
      int col = bn0 + wn + j * 16 + l15;
      float bs = bias[col];
#pragma unroll
      for (int r = 0; r < 4; ++r) {
        int row = bm0 + wm + i * 16 + lg * 4 + r;
        Cf[(size_t)row * N + col] = acc[i][j][r] + bs;
      }
    }
}

// ---------------- causal flash attention, 32x32 MFMA + permlane P-redistribution ---
// block: 4 waves; wave owns 32 q rows (QBLK=128/block), KVBLK=64, dbuf LDS.
__global__ __launch_bounds__(256) void attn_kernel(const bf16* __restrict__ Qh,
                                                   const bf16* __restrict__ Kh,
                                                   const bf16* __restrict__ VhT,
                                                   bf16* __restrict__ aout) {
  __shared__ __align__(16) bf16 lK[2][64 * 64];
  __shared__ __align__(16) bf16 lVT[2][64 * 64];
  const int tid  = threadIdx.x;
  const int lane = tid & 63, wave = tid >> 6;
  const int l31  = lane & 31;
  const int hi   = lane >> 5;
  const int bh   = blockIdx.x;              // 0..63
  const int qt   = 15 - blockIdx.y;         // heavy bands first
  const int b    = bh >> 4, h = bh & 15;
  const int q0w  = qt * 128 + wave * 32;
  const size_t tb = (size_t)b * TT;
  const int swz  = (l31 & 7) << 4;          // row-XOR swizzle (same for rows r, r+32)

  // Q fragments, pre-scaled by 0.125*log2(e): qfr[dc] = Q[q=q0w+l31][16dc+8hi+j]
  const float QSCALE = 0.18033688011112042f;
  bf16x8 qfr[4];
  {
    const bf16* qrow = Qh + ((size_t)bh * TT + q0w + l31) * HDIM;
#pragma unroll
    for (int dc = 0; dc < 4; ++dc) {
      bf16x8 v = *reinterpret_cast<const bf16x8*>(qrow + dc * 16 + hi * 8);
      bf16x8 o;
#pragma unroll
      for (int j = 0; j < 8; ++j) o[j] = (bf16)((float)v[j] * QSCALE);
      qfr[dc] = o;
    }
  }

  f32x16 oacc[2] = {};          // O[q=l31][d = 32dh + (r&3)+8(r>>2)+4hi]
  float mrun = -3e38f, srun = 0.0f;

  // staging (thread handles chunks tid and tid+256 of the 64x64 tiles)
  const int r0 = tid >> 3, sg = tid & 7;
  const bf16* kS0 = Kh + ((size_t)bh * TT + r0) * HDIM + (size_t)(sg ^ (r0 & 7)) * 8;
  const bf16* kS1 = Kh + ((size_t)bh * TT + 32 + r0) * HDIM + (size_t)(sg ^ (r0 & 7)) * 8;
  const bf16* vS0 = VhT + ((size_t)bh * HDIM + r0) * TT + (size_t)(sg ^ (r0 & 7)) * 8;
  const bf16* vS1 = VhT + ((size_t)bh * HDIM + 32 + r0) * TT + (size_t)(sg ^ (r0 & 7)) * 8;

  const int nkv = 2 * qt + 2;

  // prologue: stage tile 0 into buf 0
  gload_lds16(kS0, &lK[0][tid * 8]);
  gload_lds16(kS1, &lK[0][(tid + 256) * 8]);
  gload_lds16(vS0, &lVT[0][tid * 8]);
  gload_lds16(vS1, &lVT[0][(tid + 256) * 8]);
  __syncthreads();

  int cur = 0;
  for (int t = 0; t < nkv; ++t) {
    const int kv0 = t * 64;
    if (t + 1 < nkv) {
      const int kvn = kv0 + 64;
      gload_lds16(kS0 + (size_t)kvn * HDIM, &lK[cur ^ 1][tid * 8]);
      gload_lds16(kS1 + (size_t)kvn * HDIM, &lK[cur ^ 1][(tid + 256) * 8]);
      gload_lds16(vS0 + kvn, &lVT[cur ^ 1][tid * 8]);
      gload_lds16(vS1 + kvn, &lVT[cur ^ 1][(tid + 256) * 8]);
    }

    if (kv0 <= q0w + 31) {
      const char* kbase = (const char*)&lK[cur][0];
      const char* vbase = (const char*)&lVT[cur][0];

      // ---- QK^T: S^T[kv][q], lane holds S[q=l31][kv = (r&3)+8(r>>2)+4hi (+32 for s1)]
      f32x16 s0 = {}, s1 = {};
      __builtin_amdgcn_s_setprio(1);
#pragma unroll
      for (int dc = 0; dc < 4; ++dc) {
        bf16x8 kf = *reinterpret_cast<const bf16x8*>(
            kbase + l31 * 128 + (((2 * dc + hi) * 16) ^ swz));
        s0 = __builtin_amdgcn_mfma_f32_32x32x16_bf16(kf, qfr[dc], s0, 0, 0, 0);
      }
#pragma unroll
      for (int dc = 0; dc < 4; ++dc) {
        bf16x8 kf = *reinterpret_cast<const bf16x8*>(
            kbase + (32 + l31) * 128 + (((2 * dc + hi) * 16) ^ swz));
        s1 = __builtin_amdgcn_mfma_f32_32x32x16_bf16(kf, qfr[dc], s1, 0, 0, 0);
      }
      __builtin_amdgcn_s_setprio(0);

      // ---- causal mask (diagonal-crossing tiles only)
      if (kv0 + 63 > q0w) {
        const int qg = q0w + l31;
#pragma unroll
        for (int r = 0; r < 16; ++r) {
          const int kvb = kv0 + (r & 3) + 8 * (r >> 2) + 4 * hi;
          if (kvb > qg)      s0[r] = -3e38f;
          if (kvb + 32 > qg) s1[r] = -3e38f;
        }
      }

      // ---- row max (q = l31): in-lane tree + one xor-32 exchange
      float m8[8];
#pragma unroll
      for (int i = 0; i < 8; ++i)
        m8[i] = fmaxf(fmaxf(s0[i], s0[i + 8]), fmaxf(s1[i], s1[i + 8]));
#pragma unroll
      for (int st = 4; st > 0; st >>= 1)
#pragma unroll
        for (int i = 0; i < st; ++i) m8[i] = fmaxf(m8[i], m8[i + st]);
      float mx = fmaxf(m8[0], __shfl_xor(m8[0], 32));
      const float mnew = fmaxf(mrun, mx);
      const float corr = __builtin_amdgcn_exp2f(mrun - mnew);
      mrun = mnew;

      // ---- exp2 + partial rowsum (cross-lane sum deferred to epilogue)
      float psum = 0.0f;
#pragma unroll
      for (int r = 0; r < 16; ++r) {
        s0[r] = __builtin_amdgcn_exp2f(s0[r] - mnew);
        s1[r] = __builtin_amdgcn_exp2f(s1[r] - mnew);
        psum += s0[r] + s1[r];
      }
      srun = srun * corr + psum;
#pragma unroll
      for (int r = 0; r < 16; ++r) { oacc[0][r] *= corr; oacc[1][r] *= corr; }

      // ---- P -> B-frag via pack + permlane32_swap (T12)
      // pw[c] delivers P[q=l31][kv = 16c + 8hi + j], j=0..7
      union { u32 w[4]; bf16x8 v; } pw[4];
#pragma unroll
      for (int cl = 0; cl < 2; ++cl) {
        {
          u32 a01 = pkbf(s0[8 * cl + 0], s0[8 * cl + 1]);
          u32 a23 = pkbf(s0[8 * cl + 2], s0[8 * cl + 3]);
          u32 b01 = pkbf(s0[8 * cl + 4], s0[8 * cl + 5]);
          u32 b23 = pkbf(s0[8 * cl + 6], s0[8 * cl + 7]);
          asm("v_permlane32_swap_b32 %0, %1" : "+v"(a01), "+v"(b01));
          asm("v_permlane32_swap_b32 %0, %1" : "+v"(a23), "+v"(b23));
          pw[cl].w[0] = a01; pw[cl].w[1] = a23; pw[cl].w[2] = b01; pw[cl].w[3] = b23;
        }
        {
          u32 a01 = pkbf(s1[8 * cl + 0], s1[8 * cl + 1]);
          u32 a23 = pkbf(s1[8 * cl + 2], s1[8 * cl + 3]);
          u32 b01 = pkbf(s1[8 * cl + 4], s1[8 * cl + 5]);
          u32 b23 = pkbf(s1[8 * cl + 6], s1[8 * cl + 7]);
          asm("v_permlane32_swap_b32 %0, %1" : "+v"(a01), "+v"(b01));
          asm("v_permlane32_swap_b32 %0, %1" : "+v"(a23), "+v"(b23));
          pw[2 + cl].w[0] = a01; pw[2 + cl].w[1] = a23; pw[2 + cl].w[2] = b01; pw[2 + cl].w[3] = b23;
        }
      }

      // ---- PV: O^T += V^T-frag x P-frag
      __builtin_amdgcn_s_setprio(1);
#pragma unroll
      for (int dh = 0; dh < 2; ++dh) {
        const char* vrow = vbase + (32 * dh + l31) * 128;
#pragma unroll
        for (int c = 0; c < 4; ++c) {
          bf16x8 vf = *reinterpret_cast<const bf16x8*>(vrow + (((2 * c + hi) * 16) ^ swz));
          oacc[dh] = __builtin_amdgcn_mfma_f32_32x32x16_bf16(vf, pw[c].v, oacc[dh], 0, 0, 0);
        }
      }
      __builtin_amdgcn_s_setprio(0);
    }
    __syncthreads();   // drains prefetch + protects dbuf swap
    cur ^= 1;
  }

  // ---- epilogue: cross-lane rowsum, divide, store
  srun += __shfl_xor(srun, 32);
  const float inv = 1.0f / srun;
  const int q = q0w + l31;
  bf16* orow = aout + (tb + q) * (size_t)EMBED + h * HDIM;
#pragma unroll
  for (int dh = 0; dh < 2; ++dh)
#pragma unroll
    for (int rb = 0; rb < 4; ++rb) {
      bf16x4 o4;
#pragma unroll
      for (int k = 0; k < 4; ++k) o4[k] = (bf16)(oacc[dh][4 * rb + k] * inv);
      *reinterpret_cast<bf16x4*>(orow + 32 * dh + 8 * rb + 4 * hi) = o4;
    }
}

extern "C" void kernel_launch(void* const* d_in, const int* in_sizes, int n_in,
                              void* d_out, int out_size, void* d_ws, size_t ws_size,
                              hipStream_t stream) {
  const float* x      = (const float*)d_in[0];
  const float* qkv_w  = (const float*)d_in[1];
  const float* qkv_b  = (const float*)d_in[2];
  const float* proj_w = (const float*)d_in[3];
  const float* proj_b = (const float*)d_in[4];
  float* out = (float*)d_out;

  const size_t QSZ = (size_t)BB * NHEAD * TT * HDIM;   // 8,388,608 elems per tensor
  char* ws = (char*)d_ws;
  bf16* xb    = (bf16*)ws;
  bf16* wqkv  = xb + (size_t)MTOK * EMBED;
  bf16* wproj = wqkv + (size_t)C3 * EMBED;
  bf16* Qh    = wproj + (size_t)EMBED * EMBED;
  bf16* Kh    = Qh + QSZ;
  bf16* VhT   = Kh + QSZ;
  bf16* aob   = xb;   // alias: xb dead after gemm_qkv

  cvt_kernel<<<dim3((MTOK * EMBED / 4 + 255) / 256), dim3(256), 0, stream>>>(x, xb, MTOK * EMBED);
  cvt_kernel<<<dim3((C3 * EMBED / 4 + 255) / 256), dim3(256), 0, stream>>>(qkv_w, wqkv, C3 * EMBED);
  cvt_kernel<<<dim3((EMBED * EMBED / 4 + 255) / 256), dim3(256), 0, stream>>>(proj_w, wproj, EMBED * EMBED);

  gemm_qkv<<<dim3(C3 / 128, MTOK / 128), dim3(256), 0, stream>>>(xb, wqkv, qkv_b, Qh, Kh, VhT);

  attn_kernel<<<dim3(BB * NHEAD, TT / 128), dim3(256), 0, stream>>>(Qh, Kh, VhT, aob);

  gemm_bt<<<dim3(EMBED / 128, MTOK / 128), dim3(256), 0, stream>>>(
      aob, wproj, proj_b, out, MTOK, EMBED, EMBED);
}

// Round 5
// 177.389 us; speedup vs baseline: 2.9577x; 1.0732x over previous
//
#include <hip/hip_runtime.h>

#define EMBED 1024
#define C3    3072
#define NHEAD 16
#define HDIM  64
#define BB    4
#define TT    2048
#define MTOK  8192   // BB*TT

typedef __bf16 bf16;
typedef __bf16 bf16x4 __attribute__((ext_vector_type(4)));
typedef __bf16 bf16x8 __attribute__((ext_vector_type(8)));
typedef float  f32x4  __attribute__((ext_vector_type(4)));
typedef float  f32x16 __attribute__((ext_vector_type(16)));
typedef unsigned int u32;

__device__ __forceinline__ void gload_lds16(const bf16* g, bf16* l) {
  __builtin_amdgcn_global_load_lds((__attribute__((address_space(1))) void*)g,
                                   (__attribute__((address_space(3))) void*)l,
                                   16, 0, 0);
}

__device__ __forceinline__ u32 pkbf(float lo, float hi_) {
  union { bf16 h[2]; u32 w; } u;
  u.h[0] = (bf16)lo; u.h[1] = (bf16)hi_;
  return u.w;
}

// ---------------- fp32 -> bf16 convert ----------------
__global__ __launch_bounds__(256) void cvt_kernel(const float* __restrict__ in,
                                                  bf16* __restrict__ out, int n) {
  int i = (blockIdx.x * blockDim.x + threadIdx.x) * 4;
  if (i >= n) return;
  float4 v = *reinterpret_cast<const float4*>(in + i);
  bf16x4 o;
  o[0] = (bf16)v.x; o[1] = (bf16)v.y; o[2] = (bf16)v.z; o[3] = (bf16)v.w;
  *reinterpret_cast<bf16x4*>(out + i) = o;
}

// ---------------- GEMM1: qkv = x @ qkv_w^T + b, split into per-head layouts --------
__global__ __launch_bounds__(256) void gemm_qkv(const bf16* __restrict__ A,   // [8192][1024]
                                                const bf16* __restrict__ W,   // [3072][1024]
                                                const float* __restrict__ bias,
                                                bf16* __restrict__ Qh,
                                                bf16* __restrict__ Kh,
                                                bf16* __restrict__ VhT) {
  const int K = EMBED;
  __shared__ __align__(16) bf16 lA[128 * 32];
  __shared__ __align__(16) bf16 lB[128 * 32];
  const int tid  = threadIdx.x;
  const int lane = tid & 63;
  const int wave = tid >> 6;
  const int wm   = (wave >> 1) * 64;
  const int wn   = (wave & 1) * 64;
  const int bn0  = blockIdx.x * 128;
  const int bm0  = blockIdx.y * 128;
  const int l15  = lane & 15, lg = lane >> 4;
  const int srow = tid >> 2;
  const int sseg = tid & 3;

  f32x4 acc[4][4] = {};

  for (int kt = 0; kt < K; kt += 32) {
#pragma unroll
    for (int c = 0; c < 2; ++c) {
      int row = c * 64 + srow;
      gload_lds16(A + (size_t)(bm0 + row) * K + kt + sseg * 8, &lA[(c * 256 + tid) * 8]);
      gload_lds16(W + (size_t)(bn0 + row) * K + kt + sseg * 8, &lB[(c * 256 + tid) * 8]);
    }
    __syncthreads();
    bf16x8 af[4], bf_[4];
#pragma unroll
    for (int i = 0; i < 4; ++i)
      af[i] = *reinterpret_cast<const bf16x8*>(&lA[(wm + i * 16 + l15) * 32 + lg * 8]);
#pragma unroll
    for (int j = 0; j < 4; ++j)
      bf_[j] = *reinterpret_cast<const bf16x8*>(&lB[(wn + j * 16 + l15) * 32 + lg * 8]);
#pragma unroll
    for (int i = 0; i < 4; ++i)
#pragma unroll
      for (int j = 0; j < 4; ++j)
        acc[i][j] = __builtin_amdgcn_mfma_f32_16x16x32_bf16(af[i], bf_[j], acc[i][j], 0, 0, 0);
    __syncthreads();
  }

  const int sec = bn0 >> 10;   // 0=Q 1=K 2=V, uniform per block
#pragma unroll
  for (int i = 0; i < 4; ++i)
#pragma unroll
    for (int j = 0; j < 4; ++j) {
      const int col = bn0 + wn + j * 16 + l15;
      const float bs = bias[col];
      const int c2 = col & 1023, hh = c2 >> 6, dd = c2 & 63;
      const int rowb = bm0 + wm + i * 16 + lg * 4;
      const int bb = rowb >> 11, t0 = rowb & 2047;
      const int bh = bb * 16 + hh;
      if (sec < 2) {
        bf16* dst = (sec ? Kh : Qh) + ((size_t)bh * TT + t0) * HDIM + dd;
#pragma unroll
        for (int r = 0; r < 4; ++r) dst[(size_t)r * HDIM] = (bf16)(acc[i][j][r] + bs);
      } else {
        bf16x4 o4;
#pragma unroll
        for (int r = 0; r < 4; ++r) o4[r] = (bf16)(acc[i][j][r] + bs);
        *reinterpret_cast<bf16x4*>(VhT + ((size_t)bh * HDIM + dd) * TT + t0) = o4;
      }
    }
}

// ---------------- GEMM2: out = A @ W^T + b (fp32 out) ----------------
__global__ __launch_bounds__(256) void gemm_bt(const bf16* __restrict__ A,
                                               const bf16* __restrict__ W,
                                               const float* __restrict__ bias,
                                               float* __restrict__ Cf,
                                               int M, int N, int K) {
  __shared__ __align__(16) bf16 lA[128 * 32];
  __shared__ __align__(16) bf16 lB[128 * 32];
  const int tid  = threadIdx.x;
  const int lane = tid & 63;
  const int wave = tid >> 6;
  const int wm   = (wave >> 1) * 64;
  const int wn   = (wave & 1) * 64;
  const int bn0  = blockIdx.x * 128;
  const int bm0  = blockIdx.y * 128;
  const int l15  = lane & 15, lg = lane >> 4;
  const int srow = tid >> 2;
  const int sseg = tid & 3;

  f32x4 acc[4][4] = {};

  for (int kt = 0; kt < K; kt += 32) {
#pragma unroll
    for (int c = 0; c < 2; ++c) {
      int row = c * 64 + srow;
      gload_lds16(A + (size_t)(bm0 + row) * K + kt + sseg * 8, &lA[(c * 256 + tid) * 8]);
      gload_lds16(W + (size_t)(bn0 + row) * K + kt + sseg * 8, &lB[(c * 256 + tid) * 8]);
    }
    __syncthreads();
    bf16x8 af[4], bf_[4];
#pragma unroll
    for (int i = 0; i < 4; ++i)
      af[i] = *reinterpret_cast<const bf16x8*>(&lA[(wm + i * 16 + l15) * 32 + lg * 8]);
#pragma unroll
    for (int j = 0; j < 4; ++j)
      bf_[j] = *reinterpret_cast<const bf16x8*>(&lB[(wn + j * 16 + l15) * 32 + lg * 8]);
#pragma unroll
    for (int i = 0; i < 4; ++i)
#pragma unroll
      for (int j = 0; j < 4; ++j)
        acc[i][j] = __builtin_amdgcn_mfma_f32_16x16x32_bf16(af[i], bf_[j], acc[i][j], 0, 0, 0);
    __syncthreads();
  }

#pragma unroll
  for (int i = 0; i < 4; ++i)
#pragma unroll
    for (int j = 0; j < 4; ++j) {
      int col = bn0 + wn + j * 16 + l15;
      float bs = bias[col];
#pragma unroll
      for (int r = 0; r < 4; ++r) {
        int row = bm0 + wm + i * 16 + lg * 4 + r;
        Cf[(size_t)row * N + col] = acc[i][j][r] + bs;
      }
    }
}

// ---------------- one 32q x 64kv attention tile for one band ----------------
__device__ __forceinline__ void attn_tile(const char* kbase, const char* vbase,
                                          const bf16x8 (&qfr)[4], f32x16 (&oacc)[2],
                                          float& mrun, float& srun,
                                          const int kv0, const int q0w,
                                          const int l31, const int hi, const int swz) {
  // ---- QK^T: lane holds S[q=l31][kv = (r&3)+8(r>>2)+4hi (+32 for s1)]
  f32x16 s0 = {}, s1 = {};
  __builtin_amdgcn_s_setprio(1);
#pragma unroll
  for (int dc = 0; dc < 4; ++dc) {
    bf16x8 kf = *reinterpret_cast<const bf16x8*>(
        kbase + l31 * 128 + (((2 * dc + hi) * 16) ^ swz));
    s0 = __builtin_amdgcn_mfma_f32_32x32x16_bf16(kf, qfr[dc], s0, 0, 0, 0);
  }
#pragma unroll
  for (int dc = 0; dc < 4; ++dc) {
    bf16x8 kf = *reinterpret_cast<const bf16x8*>(
        kbase + (32 + l31) * 128 + (((2 * dc + hi) * 16) ^ swz));
    s1 = __builtin_amdgcn_mfma_f32_32x32x16_bf16(kf, qfr[dc], s1, 0, 0, 0);
  }
  __builtin_amdgcn_s_setprio(0);

  // ---- causal mask (diagonal-crossing tiles only)
  if (kv0 + 63 > q0w) {
    const int qg = q0w + l31;
#pragma unroll
    for (int r = 0; r < 16; ++r) {
      const int kvb = kv0 + (r & 3) + 8 * (r >> 2) + 4 * hi;
      if (kvb > qg)      s0[r] = -3e38f;
      if (kvb + 32 > qg) s1[r] = -3e38f;
    }
  }

  // ---- row max (q = l31): in-lane tree + one xor-32 exchange
  float m8[8];
#pragma unroll
  for (int i = 0; i < 8; ++i)
    m8[i] = fmaxf(fmaxf(s0[i], s0[i + 8]), fmaxf(s1[i], s1[i + 8]));
#pragma unroll
  for (int st = 4; st > 0; st >>= 1)
#pragma unroll
    for (int i = 0; i < st; ++i) m8[i] = fmaxf(m8[i], m8[i + st]);
  float mx = fmaxf(m8[0], __shfl_xor(m8[0], 32));

  // ---- defer-max (T13): only rescale when the tile max grew materially
  float mref = mrun;
  if (!__all(mx <= mrun + 8.0f)) {
    const float mnew = fmaxf(mrun, mx);
    const float corr = __builtin_amdgcn_exp2f(mrun - mnew);
    mrun = mnew; mref = mnew;
    srun *= corr;
#pragma unroll
    for (int r = 0; r < 16; ++r) { oacc[0][r] *= corr; oacc[1][r] *= corr; }
  }

  // ---- exp2 + partial rowsum (cross-lane sum deferred to epilogue)
  float psum = 0.0f;
#pragma unroll
  for (int r = 0; r < 16; ++r) {
    s0[r] = __builtin_amdgcn_exp2f(s0[r] - mref);
    s1[r] = __builtin_amdgcn_exp2f(s1[r] - mref);
    psum += s0[r] + s1[r];
  }
  srun += psum;

  // ---- P -> B-frag via pack + permlane32_swap (T12)
  union { u32 w[4]; bf16x8 v; } pw[4];
#pragma unroll
  for (int cl = 0; cl < 2; ++cl) {
    {
      u32 a01 = pkbf(s0[8 * cl + 0], s0[8 * cl + 1]);
      u32 a23 = pkbf(s0[8 * cl + 2], s0[8 * cl + 3]);
      u32 b01 = pkbf(s0[8 * cl + 4], s0[8 * cl + 5]);
      u32 b23 = pkbf(s0[8 * cl + 6], s0[8 * cl + 7]);
      asm("v_permlane32_swap_b32 %0, %1" : "+v"(a01), "+v"(b01));
      asm("v_permlane32_swap_b32 %0, %1" : "+v"(a23), "+v"(b23));
      pw[cl].w[0] = a01; pw[cl].w[1] = a23; pw[cl].w[2] = b01; pw[cl].w[3] = b23;
    }
    {
      u32 a01 = pkbf(s1[8 * cl + 0], s1[8 * cl + 1]);
      u32 a23 = pkbf(s1[8 * cl + 2], s1[8 * cl + 3]);
      u32 b01 = pkbf(s1[8 * cl + 4], s1[8 * cl + 5]);
      u32 b23 = pkbf(s1[8 * cl + 6], s1[8 * cl + 7]);
      asm("v_permlane32_swap_b32 %0, %1" : "+v"(a01), "+v"(b01));
      asm("v_permlane32_swap_b32 %0, %1" : "+v"(a23), "+v"(b23));
      pw[2 + cl].w[0] = a01; pw[2 + cl].w[1] = a23; pw[2 + cl].w[2] = b01; pw[2 + cl].w[3] = b23;
    }
  }

  // ---- PV: O^T += V^T-frag x P-frag
  __builtin_amdgcn_s_setprio(1);
#pragma unroll
  for (int dh = 0; dh < 2; ++dh) {
    const char* vrow = vbase + (32 * dh + l31) * 128;
#pragma unroll
    for (int c = 0; c < 4; ++c) {
      bf16x8 vf = *reinterpret_cast<const bf16x8*>(vrow + (((2 * c + hi) * 16) ^ swz));
      oacc[dh] = __builtin_amdgcn_mfma_f32_32x32x16_bf16(vf, pw[c].v, oacc[dh], 0, 0, 0);
    }
  }
  __builtin_amdgcn_s_setprio(0);
}

// ---------------- causal flash attention: paired q-bands, shared KV stream ----------
// block = (bh, pair p): bands qt=15-p (H) and qt=p (L); 4 waves x 32 q rows per band.
__global__ __launch_bounds__(256, 2) void attn_kernel(const bf16* __restrict__ Qh,
                                                      const bf16* __restrict__ Kh,
                                                      const bf16* __restrict__ VhT,
                                                      bf16* __restrict__ aout) {
  __shared__ __align__(16) bf16 lK[2][64 * 64];
  __shared__ __align__(16) bf16 lVT[2][64 * 64];
  const int tid  = threadIdx.x;
  const int lane = tid & 63, wave = tid >> 6;
  const int l31  = lane & 31;
  const int hi   = lane >> 5;
  const int bid  = blockIdx.x;              // 0..511, linear: same-bh blocks land on one XCD
  const int bh   = bid & 63;
  const int p    = bid >> 6;                // 0..7
  const int qtH  = 15 - p, qtL = p;
  const int b    = bh >> 4, h = bh & 15;
  const int q0H  = qtH * 128 + wave * 32;
  const int q0L  = qtL * 128 + wave * 32;
  const size_t tb = (size_t)b * TT;
  const int swz  = (l31 & 7) << 4;

  // Q fragments for both bands, pre-scaled by 0.125*log2(e)
  const float QSCALE = 0.18033688011112042f;
  bf16x8 qfrH[4], qfrL[4];
  {
    const bf16* qrowH = Qh + ((size_t)bh * TT + q0H + l31) * HDIM;
    const bf16* qrowL = Qh + ((size_t)bh * TT + q0L + l31) * HDIM;
#pragma unroll
    for (int dc = 0; dc < 4; ++dc) {
      bf16x8 vH = *reinterpret_cast<const bf16x8*>(qrowH + dc * 16 + hi * 8);
      bf16x8 vL = *reinterpret_cast<const bf16x8*>(qrowL + dc * 16 + hi * 8);
      bf16x8 oH, oL;
#pragma unroll
      for (int j = 0; j < 8; ++j) {
        oH[j] = (bf16)((float)vH[j] * QSCALE);
        oL[j] = (bf16)((float)vL[j] * QSCALE);
      }
      qfrH[dc] = oH; qfrL[dc] = oL;
    }
  }

  f32x16 oaccH[2] = {}, oaccL[2] = {};
  float mH = -3e38f, sH = 0.0f, mL = -3e38f, sL = 0.0f;

  // staging (thread handles chunks tid and tid+256 of the 64x64 tiles)
  const int r0 = tid >> 3, sg = tid & 7;
  const bf16* kS0 = Kh + ((size_t)bh * TT + r0) * HDIM + (size_t)(sg ^ (r0 & 7)) * 8;
  const bf16* kS1 = Kh + ((size_t)bh * TT + 32 + r0) * HDIM + (size_t)(sg ^ (r0 & 7)) * 8;
  const bf16* vS0 = VhT + ((size_t)bh * HDIM + r0) * TT + (size_t)(sg ^ (r0 & 7)) * 8;
  const bf16* vS1 = VhT + ((size_t)bh * HDIM + 32 + r0) * TT + (size_t)(sg ^ (r0 & 7)) * 8;

  const int nkv = 2 * qtH + 2;

  // prologue: stage tile 0 into buf 0
  gload_lds16(kS0, &lK[0][tid * 8]);
  gload_lds16(kS1, &lK[0][(tid + 256) * 8]);
  gload_lds16(vS0, &lVT[0][tid * 8]);
  gload_lds16(vS1, &lVT[0][(tid + 256) * 8]);
  __syncthreads();

  int cur = 0;
  for (int t = 0; t < nkv; ++t) {
    const int kv0 = t * 64;
    if (t + 1 < nkv) {
      const int kvn = kv0 + 64;
      gload_lds16(kS0 + (size_t)kvn * HDIM, &lK[cur ^ 1][tid * 8]);
      gload_lds16(kS1 + (size_t)kvn * HDIM, &lK[cur ^ 1][(tid + 256) * 8]);
      gload_lds16(vS0 + kvn, &lVT[cur ^ 1][tid * 8]);
      gload_lds16(vS1 + kvn, &lVT[cur ^ 1][(tid + 256) * 8]);
    }

    const char* kbase = (const char*)&lK[cur][0];
    const char* vbase = (const char*)&lVT[cur][0];
    if (kv0 <= q0H + 31)
      attn_tile(kbase, vbase, qfrH, oaccH, mH, sH, kv0, q0H, l31, hi, swz);
    if (kv0 <= q0L + 31)
      attn_tile(kbase, vbase, qfrL, oaccL, mL, sL, kv0, q0L, l31, hi, swz);

    __syncthreads();   // drains prefetch + protects dbuf swap
    cur ^= 1;
  }

  // ---- epilogue: cross-lane rowsum, divide, store (both bands)
#pragma unroll
  for (int band = 0; band < 2; ++band) {
    const f32x16* oacc = band ? oaccL : oaccH;
    float sr = band ? sL : sH;
    sr += __shfl_xor(sr, 32);
    const float inv = 1.0f / sr;
    const int q = (band ? q0L : q0H) + l31;
    bf16* orow = aout + (tb + q) * (size_t)EMBED + h * HDIM;
#pragma unroll
    for (int dh = 0; dh < 2; ++dh)
#pragma unroll
      for (int rb = 0; rb < 4; ++rb) {
        bf16x4 o4;
#pragma unroll
        for (int k = 0; k < 4; ++k) o4[k] = (bf16)(oacc[dh][4 * rb + k] * inv);
        *reinterpret_cast<bf16x4*>(orow + 32 * dh + 8 * rb + 4 * hi) = o4;
      }
  }
}

extern "C" void kernel_launch(void* const* d_in, const int* in_sizes, int n_in,
                              void* d_out, int out_size, void* d_ws, size_t ws_size,
                              hipStream_t stream) {
  const float* x      = (const float*)d_in[0];
  const float* qkv_w  = (const float*)d_in[1];
  const float* qkv_b  = (const float*)d_in[2];
  const float* proj_w = (const float*)d_in[3];
  const float* proj_b = (const float*)d_in[4];
  float* out = (float*)d_out;

  const size_t QSZ = (size_t)BB * NHEAD * TT * HDIM;   // 8,388,608 elems per tensor
  char* ws = (char*)d_ws;
  bf16* xb    = (bf16*)ws;
  bf16* wqkv  = xb + (size_t)MTOK * EMBED;
  bf16* wproj = wqkv + (size_t)C3 * EMBED;
  bf16* Qh    = wproj + (size_t)EMBED * EMBED;
  bf16* Kh    = Qh + QSZ;
  bf16* VhT   = Kh + QSZ;
  bf16* aob   = xb;   // alias: xb dead after gemm_qkv

  cvt_kernel<<<dim3((MTOK * EMBED / 4 + 255) / 256), dim3(256), 0, stream>>>(x, xb, MTOK * EMBED);
  cvt_kernel<<<dim3((C3 * EMBED / 4 + 255) / 256), dim3(256), 0, stream>>>(qkv_w, wqkv, C3 * EMBED);
  cvt_kernel<<<dim3((EMBED * EMBED / 4 + 255) / 256), dim3(256), 0, stream>>>(proj_w, wproj, EMBED * EMBED);

  gemm_qkv<<<dim3(C3 / 128, MTOK / 128), dim3(256), 0, stream>>>(xb, wqkv, qkv_b, Qh, Kh, VhT);

  attn_kernel<<<dim3(512), dim3(256), 0, stream>>>(Qh, Kh, VhT, aob);

  gemm_bt<<<dim3(EMBED / 128, MTOK / 128), dim3(256), 0, stream>>>(
      aob, wproj, proj_b, out, MTOK, EMBED, EMBED);
}